// Round 1
// baseline (537.599 us; speedup 1.0000x reference)
//
#include <hip/hip_runtime.h>
#include <math.h>

// Problem constants (fixed by the reference: B=16, C=256, H=W=128, K=7)
#define HW      128
#define PLANE   16384                 // 128*128
#define CHS     256
#define BATCH   16
#define CSTRIDE 16384                 // plane stride in floats
#define BSTRIDE (256 * 16384)         // batch stride in floats = 4194304

// ---------------------------------------------------------------------------
// Kernel 1: channel-wise max + mean over C=256 -> two [B,128,128] planes in ws
// Grid: 1024 blocks x 256 threads.
//   Each block: 64 float4 spatial chunks (sc = tid & 63) x 4 channel quarters
//   (cq = tid >> 6, 64 channels each). Coalesced: a wave's 64 lanes read
//   64 consecutive float4 = 1 KiB contiguous per channel slice.
// ---------------------------------------------------------------------------
__global__ __launch_bounds__(256) void reduce_kernel(
    const float* __restrict__ x, float* __restrict__ pmax, float* __restrict__ pavg)
{
    const int tid = threadIdx.x;
    const int sc  = tid & 63;
    const int cq  = tid >> 6;
    const int g   = blockIdx.x * 64 + sc;      // global float4 chunk id, 0..65535
    const int b   = g >> 12;                   // 4096 chunks per batch plane
    const int sp  = (g & 4095) << 2;           // float offset within plane

    const float* xp = x + (size_t)b * BSTRIDE + sp + (size_t)(cq << 6) * CSTRIDE;

    float4 vmax = make_float4(-INFINITY, -INFINITY, -INFINITY, -INFINITY);
    float4 vsum = make_float4(0.f, 0.f, 0.f, 0.f);

    #pragma unroll 4
    for (int c = 0; c < 64; ++c) {
        const float4 v = *(const float4*)(xp + (size_t)c * CSTRIDE);
        vmax.x = fmaxf(vmax.x, v.x); vmax.y = fmaxf(vmax.y, v.y);
        vmax.z = fmaxf(vmax.z, v.z); vmax.w = fmaxf(vmax.w, v.w);
        vsum.x += v.x; vsum.y += v.y; vsum.z += v.z; vsum.w += v.w;
    }

    __shared__ float4 smax[256];
    __shared__ float4 ssum[256];
    smax[tid] = vmax;
    ssum[tid] = vsum;
    __syncthreads();

    if (tid < 64) {
        float4 m0 = smax[tid], m1 = smax[tid + 64], m2 = smax[tid + 128], m3 = smax[tid + 192];
        float4 s0 = ssum[tid], s1 = ssum[tid + 64], s2 = ssum[tid + 128], s3 = ssum[tid + 192];
        float4 m, s;
        m.x = fmaxf(fmaxf(m0.x, m1.x), fmaxf(m2.x, m3.x));
        m.y = fmaxf(fmaxf(m0.y, m1.y), fmaxf(m2.y, m3.y));
        m.z = fmaxf(fmaxf(m0.z, m1.z), fmaxf(m2.z, m3.z));
        m.w = fmaxf(fmaxf(m0.w, m1.w), fmaxf(m2.w, m3.w));
        const float inv = 1.0f / 256.0f;
        s.x = (s0.x + s1.x + s2.x + s3.x) * inv;
        s.y = (s0.y + s1.y + s2.y + s3.y) * inv;
        s.z = (s0.z + s1.z + s2.z + s3.z) * inv;
        s.w = (s0.w + s1.w + s2.w + s3.w) * inv;
        const int gg = blockIdx.x * 64 + tid;
        *(float4*)(pmax + (size_t)gg * 4) = m;
        *(float4*)(pavg + (size_t)gg * 4) = s;
    }
}

// ---------------------------------------------------------------------------
// Kernel 2: 7x7 SAME conv on [max, avg] planes -> hsigmoid gate -> x * gate
// Grid: one block per (b, h) row = 16*128 = 2048 blocks x 256 threads.
//   Phase A: tid<128 computes the gate for its pixel (plane reads are tiny,
//            L2-resident). Phase B: all 256 threads stream 256 channels of
//            the 128-wide row as float4 (32 iters/thread).
// ---------------------------------------------------------------------------
__global__ __launch_bounds__(256) void gate_mul_kernel(
    const float* __restrict__ x,
    const float* __restrict__ pmax, const float* __restrict__ pavg,
    const float* __restrict__ cw, const float* __restrict__ cb,
    float* __restrict__ out)
{
    __shared__ float sw[98];                      // conv_w: [2][7][7]
    __shared__ __align__(16) float sgate[HW];

    const int tid = threadIdx.x;
    if (tid < 98) sw[tid] = cw[tid];
    const int b = blockIdx.x >> 7;
    const int h = blockIdx.x & 127;
    __syncthreads();

    if (tid < HW) {
        const int w = tid;
        float acc = cb[0];
        const float* pm = pmax + b * PLANE;
        const float* pa = pavg + b * PLANE;
        #pragma unroll
        for (int ky = 0; ky < 7; ++ky) {
            const int hh = h + ky - 3;
            if (hh >= 0 && hh < HW) {
                const float* prm = pm + hh * HW;
                const float* pra = pa + hh * HW;
                #pragma unroll
                for (int kx = 0; kx < 7; ++kx) {
                    const int ww = w + kx - 3;
                    if (ww >= 0 && ww < HW) {
                        acc = fmaf(sw[ky * 7 + kx],      prm[ww], acc);
                        acc = fmaf(sw[49 + ky * 7 + kx], pra[ww], acc);
                    }
                }
            }
        }
        // hsigmoid: clip(acc+3, 0, 6) / 6
        sgate[w] = fminf(fmaxf(acc + 3.0f, 0.0f), 6.0f) * (1.0f / 6.0f);
    }
    __syncthreads();

    const int wc   = tid & 31;   // float4 chunk within the 128-wide row
    const int csub = tid >> 5;   // 0..7 channel phase
    const float4 g4 = *(const float4*)(sgate + wc * 4);
    const size_t rowbase = (size_t)b * BSTRIDE + (size_t)h * HW + wc * 4;

    #pragma unroll 4
    for (int c = csub; c < CHS; c += 8) {
        const size_t off = rowbase + (size_t)c * CSTRIDE;
        const float4 v = *(const float4*)(x + off);
        float4 r;
        r.x = v.x * g4.x; r.y = v.y * g4.y; r.z = v.z * g4.z; r.w = v.w * g4.w;
        *(float4*)(out + off) = r;
    }
}

extern "C" void kernel_launch(void* const* d_in, const int* in_sizes, int n_in,
                              void* d_out, int out_size, void* d_ws, size_t ws_size,
                              hipStream_t stream)
{
    const float* x  = (const float*)d_in[0];   // [16,256,128,128] fp32
    const float* cw = (const float*)d_in[1];   // [1,2,7,7] fp32
    const float* cb = (const float*)d_in[2];   // [1] fp32
    float* out = (float*)d_out;

    float* pmax = (float*)d_ws;                        // [16,128,128]
    float* pavg = pmax + (size_t)BATCH * PLANE;        // [16,128,128]

    reduce_kernel<<<1024, 256, 0, stream>>>(x, pmax, pavg);
    gate_mul_kernel<<<2048, 256, 0, stream>>>(x, pmax, pavg, cw, cb, out);
}

// Round 2
// 499.160 us; speedup vs baseline: 1.0770x; 1.0770x over previous
//
#include <hip/hip_runtime.h>
#include <math.h>

// Problem constants (fixed by the reference: B=16, C=256, H=W=128, K=7)
#define HW      128
#define PLANE   16384                 // 128*128
#define CHS     256
#define BATCH   16
#define CSTRIDE 16384                 // plane stride in floats
#define BSTRIDE (256 * 16384)         // batch stride in floats = 4194304
#define CHUNK_B 4                     // batches per chunk: x-chunk (64 MiB) + out-chunk
                                      // (64 MiB) + planes stay < 256 MiB L3, so the
                                      // gate pass re-reads x from L3, not HBM.

typedef float vf4 __attribute__((ext_vector_type(4)));   // clang vector type for
                                                         // __builtin_nontemporal_store

// ---------------------------------------------------------------------------
// Kernel 1: channel-wise max + mean over C=256 for batches [b0, b0+CHUNK_B)
// Grid: 512 blocks x 256 threads (2 blocks/CU).
//   Each block: 32 float4 spatial chunks (sc = tid & 31) x 8 channel groups
//   (cg = tid >> 5, 32 channels each). Per half-wave: 32 consecutive float4
//   = 512 B contiguous per channel slice. unroll 8 -> 8 loads in flight.
// ---------------------------------------------------------------------------
__global__ __launch_bounds__(256) void reduce_kernel(
    const float* __restrict__ x, float* __restrict__ pmax, float* __restrict__ pavg,
    int b0)
{
    const int tid = threadIdx.x;
    const int sc  = tid & 31;
    const int cg  = tid >> 5;                  // 0..7
    const int g   = blockIdx.x * 32 + sc;      // chunk-local float4 id, 0..16383
    const int b   = b0 + (g >> 12);            // 4096 float4 per batch plane
    const int sp  = (g & 4095) << 2;           // float offset within plane

    const float* xp = x + (size_t)b * BSTRIDE + sp + (size_t)(cg << 5) * CSTRIDE;

    float4 vmax = make_float4(-INFINITY, -INFINITY, -INFINITY, -INFINITY);
    float4 vsum = make_float4(0.f, 0.f, 0.f, 0.f);

    #pragma unroll 8
    for (int c = 0; c < 32; ++c) {
        const float4 v = *(const float4*)(xp + (size_t)c * CSTRIDE);
        vmax.x = fmaxf(vmax.x, v.x); vmax.y = fmaxf(vmax.y, v.y);
        vmax.z = fmaxf(vmax.z, v.z); vmax.w = fmaxf(vmax.w, v.w);
        vsum.x += v.x; vsum.y += v.y; vsum.z += v.z; vsum.w += v.w;
    }

    __shared__ float4 smax[256];
    __shared__ float4 ssum[256];
    smax[tid] = vmax;
    ssum[tid] = vsum;
    __syncthreads();

    if (tid < 32) {
        float4 m = smax[tid];
        float4 s = ssum[tid];
        #pragma unroll
        for (int j = 1; j < 8; ++j) {
            const float4 mj = smax[tid + 32 * j];
            const float4 sj = ssum[tid + 32 * j];
            m.x = fmaxf(m.x, mj.x); m.y = fmaxf(m.y, mj.y);
            m.z = fmaxf(m.z, mj.z); m.w = fmaxf(m.w, mj.w);
            s.x += sj.x; s.y += sj.y; s.z += sj.z; s.w += sj.w;
        }
        const float inv = 1.0f / 256.0f;
        s.x *= inv; s.y *= inv; s.z *= inv; s.w *= inv;
        const int gg = blockIdx.x * 32 + tid;          // chunk-local float4 id
        const int bb = b0 + (gg >> 12);
        const int ss = (gg & 4095) << 2;
        *(float4*)(pmax + (size_t)bb * PLANE + ss) = m;
        *(float4*)(pavg + (size_t)bb * PLANE + ss) = s;
    }
}

// ---------------------------------------------------------------------------
// Kernel 2: 7x7 SAME conv on [max, avg] planes -> hsigmoid gate -> x * gate
// for batches [b0, b0+CHUNK_B). Grid: CHUNK_B*128 = 512 blocks x 256 threads,
// one block per (b, h) row. x reads should be L3-resident from kernel 1;
// out stores are nontemporal (write-once, never re-read).
// ---------------------------------------------------------------------------
__global__ __launch_bounds__(256) void gate_mul_kernel(
    const float* __restrict__ x,
    const float* __restrict__ pmax, const float* __restrict__ pavg,
    const float* __restrict__ cw, const float* __restrict__ cb,
    float* __restrict__ out, int b0)
{
    __shared__ float sw[98];                      // conv_w: [2][7][7]
    __shared__ __align__(16) float sgate[HW];

    const int tid = threadIdx.x;
    if (tid < 98) sw[tid] = cw[tid];
    const int b = b0 + (blockIdx.x >> 7);
    const int h = blockIdx.x & 127;
    __syncthreads();

    if (tid < HW) {
        const int w = tid;
        float acc = cb[0];
        const float* pm = pmax + (size_t)b * PLANE;
        const float* pa = pavg + (size_t)b * PLANE;
        #pragma unroll
        for (int ky = 0; ky < 7; ++ky) {
            const int hh = h + ky - 3;
            if (hh >= 0 && hh < HW) {
                const float* prm = pm + hh * HW;
                const float* pra = pa + hh * HW;
                #pragma unroll
                for (int kx = 0; kx < 7; ++kx) {
                    const int ww = w + kx - 3;
                    if (ww >= 0 && ww < HW) {
                        acc = fmaf(sw[ky * 7 + kx],      prm[ww], acc);
                        acc = fmaf(sw[49 + ky * 7 + kx], pra[ww], acc);
                    }
                }
            }
        }
        // hsigmoid: clip(acc+3, 0, 6) / 6
        sgate[w] = fminf(fmaxf(acc + 3.0f, 0.0f), 6.0f) * (1.0f / 6.0f);
    }
    __syncthreads();

    const int wc   = tid & 31;   // float4 chunk within the 128-wide row
    const int csub = tid >> 5;   // 0..7 channel phase
    const float4 g4 = *(const float4*)(sgate + wc * 4);
    const size_t rowbase = (size_t)b * BSTRIDE + (size_t)h * HW + wc * 4;

    #pragma unroll 4
    for (int c = csub; c < CHS; c += 8) {
        const size_t off = rowbase + (size_t)c * CSTRIDE;
        const float4 v = *(const float4*)(x + off);
        vf4 r;
        r.x = v.x * g4.x; r.y = v.y * g4.y; r.z = v.z * g4.z; r.w = v.w * g4.w;
        __builtin_nontemporal_store(r, (vf4*)(out + off));
    }
}

extern "C" void kernel_launch(void* const* d_in, const int* in_sizes, int n_in,
                              void* d_out, int out_size, void* d_ws, size_t ws_size,
                              hipStream_t stream)
{
    const float* x  = (const float*)d_in[0];   // [16,256,128,128] fp32
    const float* cw = (const float*)d_in[1];   // [1,2,7,7] fp32
    const float* cb = (const float*)d_in[2];   // [1] fp32
    float* out = (float*)d_out;

    float* pmax = (float*)d_ws;                        // [16,128,128]
    float* pavg = pmax + (size_t)BATCH * PLANE;        // [16,128,128]

    // Stream-ordered per-chunk pairs: reduce(chunk) loads x-chunk into L3,
    // gate(chunk) immediately re-reads it from L3 instead of HBM.
    for (int b0 = 0; b0 < BATCH; b0 += CHUNK_B) {
        reduce_kernel<<<512, 256, 0, stream>>>(x, pmax, pavg, b0);
        gate_mul_kernel<<<CHUNK_B * 128, 256, 0, stream>>>(x, pmax, pavg, cw, cb, out, b0);
    }
}